// Round 1
// baseline (38501.212 us; speedup 1.0000x reference)
//
#include <hip/hip_runtime.h>
#include <hip/hip_bf16.h>
#include <stdint.h>

typedef __bf16 bf16x8 __attribute__((ext_vector_type(8)));
typedef float f32x4 __attribute__((ext_vector_type(4)));
typedef short short8 __attribute__((ext_vector_type(8)));

#define B_ 32
#define T_ 512
#define D_ 1024
#define H_ 1024
#define NG 4096
#define L_ 3
#define NWG 256

__device__ inline unsigned short f2bf(float f) {
  unsigned u = __float_as_uint(f);
  unsigned r = (u + 0x7fffu + ((u >> 16) & 1u)) >> 16;
  return (unsigned short)r;
}
__device__ inline float bf2f(unsigned short h) {
  return __uint_as_float(((unsigned)h) << 16);
}

// ---------------- f32 -> bf16 convert (vectorized) ----------------
__global__ __launch_bounds__(256) void k_conv(const float* __restrict__ in,
                                              unsigned short* __restrict__ out, int n8) {
  int i = blockIdx.x * 256 + threadIdx.x;
  if (i >= n8) return;
  const float4* p = (const float4*)(in) + (size_t)i * 2;
  float4 a = p[0], b = p[1];
  short8 o;
  o[0] = (short)f2bf(a.x); o[1] = (short)f2bf(a.y); o[2] = (short)f2bf(a.z); o[3] = (short)f2bf(a.w);
  o[4] = (short)f2bf(b.x); o[5] = (short)f2bf(b.y); o[6] = (short)f2bf(b.z); o[7] = (short)f2bf(b.w);
  *((short8*)out + i) = o;
}

// ---------------- transpose+convert weights: (L,K,N) f32 -> (L,N,K) bf16 ----------------
__global__ __launch_bounds__(256) void k_transw(const float* __restrict__ in,
                                                unsigned short* __restrict__ out) {
  __shared__ float Tt[32][33];
  int k0 = blockIdx.x * 32, n0 = blockIdx.y * 32, l = blockIdx.z;
  const float* ip = in + (size_t)l * D_ * NG;
  unsigned short* op = out + (size_t)l * NG * D_;
  int r = threadIdx.x >> 5, c = threadIdx.x & 31;
  for (int rr = r; rr < 32; rr += 8)
    Tt[rr][c] = ip[(size_t)(k0 + rr) * NG + n0 + c];
  __syncthreads();
  for (int rr = r; rr < 32; rr += 8)
    op[(size_t)(n0 + rr) * D_ + k0 + c] = f2bf(Tt[c][rr]);
}

// ---------------- input-path GEMM: Z(M,4096) = X(M,1024) @ Wi ; WT is Wi^T (4096,1024) ----------------
#define PAD 40
__global__ __launch_bounds__(256) void k_gemm_in(const unsigned short* __restrict__ X,
                                                 const unsigned short* __restrict__ WT,
                                                 unsigned short* __restrict__ Z) {
  __shared__ short Al[128 * PAD];
  __shared__ short Bl[128 * PAD];
  int bx = blockIdx.x;
  int m0 = (bx >> 5) * 128, n0 = (bx & 31) * 128;
  int tid = threadIdx.x, lane = tid & 63, wv = tid >> 6;
  int wm = (wv >> 1) * 64, wn = (wv & 1) * 64;
  int l15 = lane & 15, lh = lane >> 4;
  f32x4 acc[4][4] = {};
  for (int s = 0; s < 32; ++s) {
    int k0 = s * 32;
    __syncthreads();
    for (int rr = 0; rr < 2; ++rr) {
      int ch = rr * 256 + tid;
      int row = ch >> 2, ko = (ch & 3) * 8;
      *(short8*)&Al[row * PAD + ko] = *(const short8*)&X[(size_t)(m0 + row) * 1024 + k0 + ko];
      *(short8*)&Bl[row * PAD + ko] = *(const short8*)&WT[(size_t)(n0 + row) * 1024 + k0 + ko];
    }
    __syncthreads();
    bf16x8 af[4], bfr[4];
    for (int mi = 0; mi < 4; ++mi)
      af[mi] = *(const bf16x8*)&Al[(wm + mi * 16 + l15) * PAD + lh * 8];
    for (int ni = 0; ni < 4; ++ni)
      bfr[ni] = *(const bf16x8*)&Bl[(wn + ni * 16 + l15) * PAD + lh * 8];
    for (int mi = 0; mi < 4; ++mi)
      for (int ni = 0; ni < 4; ++ni)
        acc[mi][ni] = __builtin_amdgcn_mfma_f32_16x16x32_bf16(af[mi], bfr[ni], acc[mi][ni], 0, 0, 0);
  }
  for (int mi = 0; mi < 4; ++mi)
    for (int ni = 0; ni < 4; ++ni)
      for (int r2 = 0; r2 < 4; ++r2) {
        int row = m0 + wm + mi * 16 + (lane >> 4) * 4 + r2;
        int col = n0 + wn + ni * 16 + l15;
        Z[(size_t)row * NG + col] = f2bf(acc[mi][ni][r2]);
      }
}

// ---------------- persistent recurrent kernel (one layer, all 512 steps) ----------------
__global__ __launch_bounds__(256) void k_rec(
    const unsigned short* __restrict__ WhT,  // (4096,1024) bf16 layer slice (Wh^T)
    const unsigned short* __restrict__ Zin,  // (B*T, 4096) bf16
    const float* __restrict__ bias,          // (4096) layer slice
    unsigned short* __restrict__ hb0,
    unsigned short* __restrict__ hb1,
    unsigned int* __restrict__ counter,
    unsigned short* __restrict__ Xnext,      // bf16 (B*T,1024) or nullptr
    float* __restrict__ yout,                // f32 (B*T,1024) (top layer) or nullptr
    float* __restrict__ hT, float* __restrict__ cT) {
  __shared__ short Wl[16 * 1024];     // 32KB, swizzled
  __shared__ float zs[4][2][64][4];   // 8KB
  __shared__ float biasS[16];
  __shared__ float pad_[14336];       // 57KB: forces 1 WG/CU (total ~98KB LDS)
  int wg = blockIdx.x, tid = threadIdx.x, lane = tid & 63, wv = tid >> 6;
  if ((uintptr_t)counter == 1) pad_[tid] = 0.f;  // never true; keeps pad_ allocated

  // stage Wh^T slice into LDS with XOR swizzle (rows r=g*4+q -> global col g*1024+wg*4+q)
  for (int cch = tid; cch < 2048; cch += 256) {
    int off = cch * 16;
    int r = off >> 11;
    int rowoff = off & 2047;
    int n = (r >> 2) * 1024 + wg * 4 + (r & 3);
    short8 v = *(const short8*)&WhT[(size_t)n * 1024 + (rowoff >> 1)];
    *(short8*)((char*)Wl + (off ^ ((r & 7) << 4))) = v;
  }
  if (tid < 16) biasS[tid] = bias[(tid >> 2) * 1024 + wg * 4 + (tid & 3)];
  __syncthreads();

  int p = tid, bb = p >> 2, q = p & 3;
  float cst = 0.f;
  int l15 = lane & 15, lh = lane >> 4;

  for (int t = 0; t < T_; ++t) {
    if (t > 0) {
      if (tid == 0) {
        unsigned target = (unsigned)(NWG * t);
        while (__hip_atomic_load(counter, __ATOMIC_ACQUIRE, __HIP_MEMORY_SCOPE_AGENT) < target)
          __builtin_amdgcn_s_sleep(2);
      }
      __syncthreads();
      __builtin_amdgcn_fence(__ATOMIC_ACQUIRE, "agent");
    }
    f32x4 a0 = {}, a1 = {};
    if (t > 0) {
      const char* hb = (const char*)((t & 1) ? hb0 : hb1);  // read buffer written at t-1
      int kbase = wv * 256 + lh * 8;
      for (int kk = 0; kk < 8; ++kk) {
        int k = kbase + kk * 32;
        int b0r = l15;
        bf16x8 av0 = *(const bf16x8*)(hb + (((b0r * 1024 + k) * 2) ^ ((b0r & 7) << 4)));
        int b1r = 16 + l15;
        bf16x8 av1 = *(const bf16x8*)(hb + (((b1r * 1024 + k) * 2) ^ ((b1r & 7) << 4)));
        bf16x8 bv = *(const bf16x8*)((const char*)Wl + (((l15 * 1024 + k) * 2) ^ ((l15 & 7) << 4)));
        a0 = __builtin_amdgcn_mfma_f32_16x16x32_bf16(av0, bv, a0, 0, 0, 0);
        a1 = __builtin_amdgcn_mfma_f32_16x16x32_bf16(av1, bv, a1, 0, 0, 0);
      }
    }
    *(f32x4*)&zs[wv][0][lane][0] = a0;
    *(f32x4*)&zs[wv][1][lane][0] = a1;
    __syncthreads();
    if (p < 128) {
      int mi = bb >> 4, lx = ((bb & 15) >> 2) * 16, rg = bb & 3;
      float zg[4];
      const unsigned short* zrow = Zin + (size_t)(bb * T_ + t) * NG + wg * 4 + q;
      for (int g = 0; g < 4; ++g) {
        int r = g * 4 + q;
        float z = zs[0][mi][lx + r][rg] + zs[1][mi][lx + r][rg] +
                  zs[2][mi][lx + r][rg] + zs[3][mi][lx + r][rg];
        zg[g] = z + bf2f(zrow[(size_t)g * 1024]) + biasS[r];
      }
      float ig = 1.f / (1.f + __expf(-zg[0]));
      float fg = 1.f / (1.f + __expf(-zg[1]));
      float e2 = __expf(-2.f * fabsf(zg[2]));
      float gg = copysignf((1.f - e2) / (1.f + e2), zg[2]);
      float og = 1.f / (1.f + __expf(-zg[3]));
      cst = fg * cst + ig * gg;
      float e2c = __expf(-2.f * fabsf(cst));
      float th = copysignf((1.f - e2c) / (1.f + e2c), cst);
      float hv = og * th;
      unsigned short hw = f2bf(hv);
      int u = wg * 4 + q;
      char* wbuf = (char*)((t & 1) ? hb1 : hb0);
      *(unsigned short*)(wbuf + (((bb * 1024 + u) * 2) ^ ((bb & 7) << 4))) = hw;
      size_t xrow = (size_t)(bb * T_ + t) * 1024 + u;
      if (Xnext) Xnext[xrow] = hw;
      else yout[xrow] = hv;
      if (t == T_ - 1) { hT[bb * 1024 + u] = hv; cT[bb * 1024 + u] = cst; }
    }
    __syncthreads();
    if (t < T_ - 1 && tid == 0) {
      __builtin_amdgcn_fence(__ATOMIC_RELEASE, "agent");
      __hip_atomic_fetch_add(counter, 1u, __ATOMIC_RELAXED, __HIP_MEMORY_SCOPE_AGENT);
    }
  }
}

extern "C" void kernel_launch(void* const* d_in, const int* in_sizes, int n_in,
                              void* d_out, int out_size, void* d_ws, size_t ws_size,
                              hipStream_t stream) {
  const float* x = (const float*)d_in[0];
  const float* Wi = (const float*)d_in[1];
  const float* Wh = (const float*)d_in[2];
  const float* bias = (const float*)d_in[3];
  float* out = (float*)d_out;
  uint8_t* W = (uint8_t*)d_ws;

  unsigned* counters = (unsigned*)W;                                // 3 counters, 128B apart
  unsigned short* hb0 = (unsigned short*)(W + 4096);                // 64KB (swizzled h)
  unsigned short* hb1 = (unsigned short*)(W + 4096 + 65536);        // 64KB
  unsigned short* Zin = (unsigned short*)(W + 0x40000);             // 128MB bf16 (B*T,4096)
  unsigned short* Xa  = (unsigned short*)(W + 0x8040000);           // 32MB bf16 (B*T,1024)
  unsigned short* Xb  = (unsigned short*)(W + 0xA040000);           // 32MB
  unsigned short* WiT = (unsigned short*)(W + 0xC040000);           // 24MB bf16 (L,4096,1024)
  unsigned short* WhT = (unsigned short*)(W + 0xD840000);           // 24MB

  hipMemsetAsync(d_ws, 0, 4096, stream);
  k_conv<<<8192, 256, 0, stream>>>(x, Xa, (B_ * T_ * D_) / 8);
  k_transw<<<dim3(32, 128, 3), 256, 0, stream>>>(Wi, WiT);
  k_transw<<<dim3(32, 128, 3), 256, 0, stream>>>(Wh, WhT);

  float* yout = out;
  float* hT = out + 16777216;
  float* cT = out + 16777216 + 98304;
  unsigned short* Xcur = Xa;
  unsigned short* Xnxt = Xb;
  for (int l = 0; l < L_; ++l) {
    k_gemm_in<<<4096, 256, 0, stream>>>(Xcur, WiT + (size_t)l * NG * 1024, Zin);
    k_rec<<<NWG, 256, 0, stream>>>(WhT + (size_t)l * NG * 1024, Zin, bias + l * NG,
                                   hb0, hb1, counters + l * 32,
                                   (l < 2) ? Xnxt : (unsigned short*)nullptr,
                                   (l < 2) ? (float*)nullptr : yout,
                                   hT + l * (B_ * H_), cT + l * (B_ * H_));
    unsigned short* tmp = Xcur; Xcur = Xnxt; Xnxt = tmp;
  }
}

// Round 2
// 26671.359 us; speedup vs baseline: 1.4435x; 1.4435x over previous
//
#include <hip/hip_runtime.h>
#include <hip/hip_bf16.h>
#include <stdint.h>

typedef __bf16 bf16x8 __attribute__((ext_vector_type(8)));
typedef float f32x4 __attribute__((ext_vector_type(4)));
typedef short short8 __attribute__((ext_vector_type(8)));

#define B_ 32
#define T_ 512
#define D_ 1024
#define H_ 1024
#define NG 4096
#define L_ 3
#define NWG 256

__device__ inline unsigned short f2bf(float f) {
  unsigned u = __float_as_uint(f);
  unsigned r = (u + 0x7fffu + ((u >> 16) & 1u)) >> 16;
  return (unsigned short)r;
}
__device__ inline float bf2f(unsigned short h) {
  return __uint_as_float(((unsigned)h) << 16);
}

// ---------------- f32 -> bf16 convert (vectorized) ----------------
__global__ __launch_bounds__(256) void k_conv(const float* __restrict__ in,
                                              unsigned short* __restrict__ out, int n8) {
  int i = blockIdx.x * 256 + threadIdx.x;
  if (i >= n8) return;
  const float4* p = (const float4*)(in) + (size_t)i * 2;
  float4 a = p[0], b = p[1];
  short8 o;
  o[0] = (short)f2bf(a.x); o[1] = (short)f2bf(a.y); o[2] = (short)f2bf(a.z); o[3] = (short)f2bf(a.w);
  o[4] = (short)f2bf(b.x); o[5] = (short)f2bf(b.y); o[6] = (short)f2bf(b.z); o[7] = (short)f2bf(b.w);
  *((short8*)out + i) = o;
}

// ---------------- transpose+convert weights: (L,K,N) f32 -> (L,N,K) bf16 ----------------
__global__ __launch_bounds__(256) void k_transw(const float* __restrict__ in,
                                                unsigned short* __restrict__ out) {
  __shared__ float Tt[32][33];
  int k0 = blockIdx.x * 32, n0 = blockIdx.y * 32, l = blockIdx.z;
  const float* ip = in + (size_t)l * D_ * NG;
  unsigned short* op = out + (size_t)l * NG * D_;
  int r = threadIdx.x >> 5, c = threadIdx.x & 31;
  for (int rr = r; rr < 32; rr += 8)
    Tt[rr][c] = ip[(size_t)(k0 + rr) * NG + n0 + c];
  __syncthreads();
  for (int rr = r; rr < 32; rr += 8)
    op[(size_t)(n0 + rr) * D_ + k0 + c] = f2bf(Tt[c][rr]);
}

// ---------------- input-path GEMM: Z(M,4096) = X(M,1024) @ Wi ; WT is Wi^T (4096,1024) ----------------
#define PAD 40
__global__ __launch_bounds__(256) void k_gemm_in(const unsigned short* __restrict__ X,
                                                 const unsigned short* __restrict__ WT,
                                                 unsigned short* __restrict__ Z) {
  __shared__ short Al[128 * PAD];
  __shared__ short Bl[128 * PAD];
  int bx = blockIdx.x;
  int m0 = (bx >> 5) * 128, n0 = (bx & 31) * 128;
  int tid = threadIdx.x, lane = tid & 63, wv = tid >> 6;
  int wm = (wv >> 1) * 64, wn = (wv & 1) * 64;
  int l15 = lane & 15, lh = lane >> 4;
  f32x4 acc[4][4] = {};
  for (int s = 0; s < 32; ++s) {
    int k0 = s * 32;
    __syncthreads();
    for (int rr = 0; rr < 2; ++rr) {
      int ch = rr * 256 + tid;
      int row = ch >> 2, ko = (ch & 3) * 8;
      *(short8*)&Al[row * PAD + ko] = *(const short8*)&X[(size_t)(m0 + row) * 1024 + k0 + ko];
      *(short8*)&Bl[row * PAD + ko] = *(const short8*)&WT[(size_t)(n0 + row) * 1024 + k0 + ko];
    }
    __syncthreads();
    bf16x8 af[4], bfr[4];
    for (int mi = 0; mi < 4; ++mi)
      af[mi] = *(const bf16x8*)&Al[(wm + mi * 16 + l15) * PAD + lh * 8];
    for (int ni = 0; ni < 4; ++ni)
      bfr[ni] = *(const bf16x8*)&Bl[(wn + ni * 16 + l15) * PAD + lh * 8];
    for (int mi = 0; mi < 4; ++mi)
      for (int ni = 0; ni < 4; ++ni)
        acc[mi][ni] = __builtin_amdgcn_mfma_f32_16x16x32_bf16(af[mi], bfr[ni], acc[mi][ni], 0, 0, 0);
  }
  for (int mi = 0; mi < 4; ++mi)
    for (int ni = 0; ni < 4; ++ni)
      for (int r2 = 0; r2 < 4; ++r2) {
        int row = m0 + wm + mi * 16 + (lane >> 4) * 4 + r2;
        int col = n0 + wn + ni * 16 + l15;
        Z[(size_t)row * NG + col] = f2bf(acc[mi][ni][r2]);
      }
}

// ---------------- persistent recurrent kernel (one layer, all 512 steps) ----------------
// Barrier: distributed monotone flags. WG w sets flags[w]=t+1 (store-release, agent)
// after finishing step t; at start of step t every WG's wave 0 polls all 256 flags
// (64 lanes x 4 relaxed agent loads) until min >= t, then acquire fence.
__global__ __launch_bounds__(256) void k_rec(
    const unsigned short* __restrict__ WhT,  // (4096,1024) bf16 layer slice (Wh^T)
    const unsigned short* __restrict__ Zin,  // (B*T, 4096) bf16
    const float* __restrict__ bias,          // (4096) layer slice
    unsigned short* __restrict__ hb0,
    unsigned short* __restrict__ hb1,
    unsigned int* __restrict__ flags,        // NWG monotone flags (zeroed per launch)
    unsigned short* __restrict__ Xnext,      // bf16 (B*T,1024) or nullptr
    float* __restrict__ yout,                // f32 (B*T,1024) (top layer) or nullptr
    float* __restrict__ hT, float* __restrict__ cT) {
  extern __shared__ char dynpad_[];          // sized 57344 at launch -> forces 1 WG/CU
  __shared__ short Wl[16 * 1024];            // 32KB, swizzled
  __shared__ float zs[4][2][64][4];          // 8KB
  __shared__ float biasS[16];
  (void)dynpad_;
  int wg = blockIdx.x, tid = threadIdx.x, lane = tid & 63, wv = tid >> 6;

  // stage Wh^T slice into LDS with XOR swizzle (rows r=g*4+q -> global col g*1024+wg*4+q)
  for (int cch = tid; cch < 2048; cch += 256) {
    int off = cch * 16;
    int r = off >> 11;
    int rowoff = off & 2047;
    int n = (r >> 2) * 1024 + wg * 4 + (r & 3);
    short8 v = *(const short8*)&WhT[(size_t)n * 1024 + (rowoff >> 1)];
    *(short8*)((char*)Wl + (off ^ ((r & 7) << 4))) = v;
  }
  if (tid < 16) biasS[tid] = bias[(tid >> 2) * 1024 + wg * 4 + (tid & 3)];
  __syncthreads();

  int p = tid, bb = p >> 2, q = p & 3;
  float cst = 0.f;
  int l15 = lane & 15, lh = lane >> 4;
  bool act = (p < 128);

  for (int t = 0; t < T_; ++t) {
    // ---- prefetch this step's Zin gate pre-activations (independent of barrier) ----
    unsigned short zv0 = 0, zv1 = 0, zv2 = 0, zv3 = 0;
    if (act) {
      const unsigned short* zrow = Zin + (size_t)(bb * T_ + t) * NG + wg * 4 + q;
      zv0 = zrow[0];
      zv1 = zrow[1024];
      zv2 = zrow[2048];
      zv3 = zrow[3072];
    }
    // ---- barrier wait: all WGs finished step t-1 ----
    if (t > 0) {
      if (wv == 0) {
        const unsigned* fl = flags + lane * 4;
        unsigned tt = (unsigned)t;
        for (;;) {
          unsigned f0 = __hip_atomic_load(fl + 0, __ATOMIC_RELAXED, __HIP_MEMORY_SCOPE_AGENT);
          unsigned f1 = __hip_atomic_load(fl + 1, __ATOMIC_RELAXED, __HIP_MEMORY_SCOPE_AGENT);
          unsigned f2 = __hip_atomic_load(fl + 2, __ATOMIC_RELAXED, __HIP_MEMORY_SCOPE_AGENT);
          unsigned f3 = __hip_atomic_load(fl + 3, __ATOMIC_RELAXED, __HIP_MEMORY_SCOPE_AGENT);
          if (__all(f0 >= tt && f1 >= tt && f2 >= tt && f3 >= tt)) break;
          __builtin_amdgcn_s_sleep(1);
        }
      }
      __syncthreads();
      __builtin_amdgcn_fence(__ATOMIC_ACQUIRE, "agent");
    }
    // ---- recurrent GEMM: z = h(t-1) @ WhT_slice ----
    f32x4 a0 = {}, a1 = {};
    if (t > 0) {
      const char* hb = (const char*)((t & 1) ? hb0 : hb1);  // buffer written at t-1
      int kbase = wv * 256 + lh * 8;
      for (int kk = 0; kk < 8; ++kk) {
        int k = kbase + kk * 32;
        int b0r = l15;
        bf16x8 av0 = *(const bf16x8*)(hb + (((b0r * 1024 + k) * 2) ^ ((b0r & 7) << 4)));
        int b1r = 16 + l15;
        bf16x8 av1 = *(const bf16x8*)(hb + (((b1r * 1024 + k) * 2) ^ ((b1r & 7) << 4)));
        bf16x8 bv = *(const bf16x8*)((const char*)Wl + (((l15 * 1024 + k) * 2) ^ ((l15 & 7) << 4)));
        a0 = __builtin_amdgcn_mfma_f32_16x16x32_bf16(av0, bv, a0, 0, 0, 0);
        a1 = __builtin_amdgcn_mfma_f32_16x16x32_bf16(av1, bv, a1, 0, 0, 0);
      }
    }
    *(f32x4*)&zs[wv][0][lane][0] = a0;
    *(f32x4*)&zs[wv][1][lane][0] = a1;
    __syncthreads();
    if (act) {
      int mi = bb >> 4, lx = ((bb & 15) >> 2) * 16, rg = bb & 3;
      float zg[4];
      unsigned short zvv[4] = {zv0, zv1, zv2, zv3};
      for (int g = 0; g < 4; ++g) {
        int r = g * 4 + q;
        float z = zs[0][mi][lx + r][rg] + zs[1][mi][lx + r][rg] +
                  zs[2][mi][lx + r][rg] + zs[3][mi][lx + r][rg];
        zg[g] = z + bf2f(zvv[g]) + biasS[r];
      }
      float ig = 1.f / (1.f + __expf(-zg[0]));
      float fg = 1.f / (1.f + __expf(-zg[1]));
      float e2 = __expf(-2.f * fabsf(zg[2]));
      float gg = copysignf((1.f - e2) / (1.f + e2), zg[2]);
      float og = 1.f / (1.f + __expf(-zg[3]));
      cst = fg * cst + ig * gg;
      float e2c = __expf(-2.f * fabsf(cst));
      float th = copysignf((1.f - e2c) / (1.f + e2c), cst);
      float hv = og * th;
      unsigned short hw = f2bf(hv);
      int u = wg * 4 + q;
      // h-state exchange: write-through (agent-scope atomic) so the release fence
      // has (almost) no dirty L2 to write back
      char* wbuf = (char*)((t & 1) ? hb1 : hb0);
      unsigned short* haddr = (unsigned short*)(wbuf + (((bb * 1024 + u) * 2) ^ ((bb & 7) << 4)));
      __hip_atomic_store(haddr, hw, __ATOMIC_RELAXED, __HIP_MEMORY_SCOPE_AGENT);
      // streaming outputs: nontemporal, keep L2 clean
      size_t xrow = (size_t)(bb * T_ + t) * 1024 + u;
      if (Xnext) __builtin_nontemporal_store(hw, &Xnext[xrow]);
      else __builtin_nontemporal_store(hv, &yout[xrow]);
      if (t == T_ - 1) { hT[bb * 1024 + u] = hv; cT[bb * 1024 + u] = cst; }
    }
    __syncthreads();  // all stores of this step drained (vmcnt0 before s_barrier)
    if (t < T_ - 1 && tid == 0) {
      __hip_atomic_store(&flags[wg], (unsigned)(t + 1), __ATOMIC_RELEASE, __HIP_MEMORY_SCOPE_AGENT);
    }
  }
}

extern "C" void kernel_launch(void* const* d_in, const int* in_sizes, int n_in,
                              void* d_out, int out_size, void* d_ws, size_t ws_size,
                              hipStream_t stream) {
  const float* x = (const float*)d_in[0];
  const float* Wi = (const float*)d_in[1];
  const float* Wh = (const float*)d_in[2];
  const float* bias = (const float*)d_in[3];
  float* out = (float*)d_out;
  uint8_t* W = (uint8_t*)d_ws;

  unsigned* flagsBase = (unsigned*)W;                               // 3 x 1KB flag arrays
  unsigned short* hb0 = (unsigned short*)(W + 4096);                // 64KB (swizzled h)
  unsigned short* hb1 = (unsigned short*)(W + 4096 + 65536);        // 64KB
  unsigned short* Zin = (unsigned short*)(W + 0x40000);             // 128MB bf16 (B*T,4096)
  unsigned short* Xa  = (unsigned short*)(W + 0x8040000);           // 32MB bf16 (B*T,1024)
  unsigned short* Xb  = (unsigned short*)(W + 0xA040000);           // 32MB
  unsigned short* WiT = (unsigned short*)(W + 0xC040000);           // 24MB bf16 (L,4096,1024)
  unsigned short* WhT = (unsigned short*)(W + 0xD840000);           // 24MB

  hipMemsetAsync(d_ws, 0, 4096, stream);
  k_conv<<<8192, 256, 0, stream>>>(x, Xa, (B_ * T_ * D_) / 8);
  k_transw<<<dim3(32, 128, 3), 256, 0, stream>>>(Wi, WiT);
  k_transw<<<dim3(32, 128, 3), 256, 0, stream>>>(Wh, WhT);

  float* yout = out;
  float* hT = out + 16777216;
  float* cT = out + 16777216 + 98304;
  unsigned short* Xcur = Xa;
  unsigned short* Xnxt = Xb;
  for (int l = 0; l < L_; ++l) {
    k_gemm_in<<<4096, 256, 0, stream>>>(Xcur, WiT + (size_t)l * NG * 1024, Zin);
    k_rec<<<NWG, 256, 57344, stream>>>(WhT + (size_t)l * NG * 1024, Zin, bias + l * NG,
                                       hb0, hb1, flagsBase + l * 256,
                                       (l < 2) ? Xnxt : (unsigned short*)nullptr,
                                       (l < 2) ? (float*)nullptr : yout,
                                       hT + l * (B_ * H_), cT + l * (B_ * H_));
    unsigned short* tmp = Xcur; Xcur = Xnxt; Xnxt = tmp;
  }
}

// Round 3
// 6262.195 us; speedup vs baseline: 6.1482x; 4.2591x over previous
//
#include <hip/hip_runtime.h>
#include <hip/hip_bf16.h>
#include <stdint.h>

typedef __bf16 bf16x8 __attribute__((ext_vector_type(8)));
typedef float f32x4 __attribute__((ext_vector_type(4)));
typedef short short8 __attribute__((ext_vector_type(8)));

#define B_ 32
#define T_ 512
#define D_ 1024
#define H_ 1024
#define NG 4096
#define L_ 3
#define NWG 256
#define HDEPTH 64            // rotating h step-buffer depth (must divide fence cadence)
#define HSTEP 32768          // ushorts per step buffer (32 batches x 1024 units)

__device__ inline unsigned short f2bf(float f) {
  unsigned u = __float_as_uint(f);
  unsigned r = (u + 0x7fffu + ((u >> 16) & 1u)) >> 16;
  return (unsigned short)r;
}
__device__ inline float bf2f(unsigned short h) {
  return __uint_as_float(((unsigned)h) << 16);
}

// ---------------- f32 -> bf16 convert (vectorized) ----------------
__global__ __launch_bounds__(256) void k_conv(const float* __restrict__ in,
                                              unsigned short* __restrict__ out, int n8) {
  int i = blockIdx.x * 256 + threadIdx.x;
  if (i >= n8) return;
  const float4* p = (const float4*)(in) + (size_t)i * 2;
  float4 a = p[0], b = p[1];
  short8 o;
  o[0] = (short)f2bf(a.x); o[1] = (short)f2bf(a.y); o[2] = (short)f2bf(a.z); o[3] = (short)f2bf(a.w);
  o[4] = (short)f2bf(b.x); o[5] = (short)f2bf(b.y); o[6] = (short)f2bf(b.z); o[7] = (short)f2bf(b.w);
  *((short8*)out + i) = o;
}

// ---------------- transpose+convert weights: (L,K,N) f32 -> (L,N,K) bf16 ----------------
__global__ __launch_bounds__(256) void k_transw(const float* __restrict__ in,
                                                unsigned short* __restrict__ out) {
  __shared__ float Tt[32][33];
  int k0 = blockIdx.x * 32, n0 = blockIdx.y * 32, l = blockIdx.z;
  const float* ip = in + (size_t)l * D_ * NG;
  unsigned short* op = out + (size_t)l * NG * D_;
  int r = threadIdx.x >> 5, c = threadIdx.x & 31;
  for (int rr = r; rr < 32; rr += 8)
    Tt[rr][c] = ip[(size_t)(k0 + rr) * NG + n0 + c];
  __syncthreads();
  for (int rr = r; rr < 32; rr += 8)
    op[(size_t)(n0 + rr) * D_ + k0 + c] = f2bf(Tt[c][rr]);
}

// ---------------- input-path GEMM: Z(M,4096) = X(M,1024) @ Wi ; WT is Wi^T (4096,1024) ----------------
#define PAD 40
__global__ __launch_bounds__(256) void k_gemm_in(const unsigned short* __restrict__ X,
                                                 const unsigned short* __restrict__ WT,
                                                 unsigned short* __restrict__ Z) {
  __shared__ short Al[128 * PAD];
  __shared__ short Bl[128 * PAD];
  int bx = blockIdx.x;
  int m0 = (bx >> 5) * 128, n0 = (bx & 31) * 128;
  int tid = threadIdx.x, lane = tid & 63, wv = tid >> 6;
  int wm = (wv >> 1) * 64, wn = (wv & 1) * 64;
  int l15 = lane & 15, lh = lane >> 4;
  f32x4 acc[4][4] = {};
  for (int s = 0; s < 32; ++s) {
    int k0 = s * 32;
    __syncthreads();
    for (int rr = 0; rr < 2; ++rr) {
      int ch = rr * 256 + tid;
      int row = ch >> 2, ko = (ch & 3) * 8;
      *(short8*)&Al[row * PAD + ko] = *(const short8*)&X[(size_t)(m0 + row) * 1024 + k0 + ko];
      *(short8*)&Bl[row * PAD + ko] = *(const short8*)&WT[(size_t)(n0 + row) * 1024 + k0 + ko];
    }
    __syncthreads();
    bf16x8 af[4], bfr[4];
    for (int mi = 0; mi < 4; ++mi)
      af[mi] = *(const bf16x8*)&Al[(wm + mi * 16 + l15) * PAD + lh * 8];
    for (int ni = 0; ni < 4; ++ni)
      bfr[ni] = *(const bf16x8*)&Bl[(wn + ni * 16 + l15) * PAD + lh * 8];
    for (int mi = 0; mi < 4; ++mi)
      for (int ni = 0; ni < 4; ++ni)
        acc[mi][ni] = __builtin_amdgcn_mfma_f32_16x16x32_bf16(af[mi], bfr[ni], acc[mi][ni], 0, 0, 0);
  }
  for (int mi = 0; mi < 4; ++mi)
    for (int ni = 0; ni < 4; ++ni)
      for (int r2 = 0; r2 < 4; ++r2) {
        int row = m0 + wm + mi * 16 + (lane >> 4) * 4 + r2;
        int col = n0 + wn + ni * 16 + l15;
        Z[(size_t)row * NG + col] = f2bf(acc[mi][ni][r2]);
      }
}

// ---------------- persistent recurrent kernel (one layer, all 512 steps) ----------------
// No per-step fences. h exchanged through a 64-deep rotating step buffer:
//   writer (WG w, thread p<128): h[bb][w*4+q] -> hh[t%64][w*128 + bb*4 + q],
//   stored with inline-asm global_store_short sc0 sc1 (write-through to MALL).
//   reader: plain cached loads of fresh addresses -> guaranteed L2 miss -> MALL fresh copy.
//   One acquire fence every HDEPTH steps clears cache lines before slot reuse.
// Flags: relaxed monotone per-WG dwords (h-stores drained by vmcnt(0) before barrier).
__global__ __launch_bounds__(256) void k_rec(
    const unsigned short* __restrict__ WhT,  // (4096,1024) bf16 layer slice (Wh^T)
    const unsigned short* __restrict__ Zin,  // (B*T, 4096) bf16
    const float* __restrict__ bias,          // (4096) layer slice
    unsigned short* __restrict__ hh,         // HDEPTH * HSTEP ushorts rotating h buffers
    unsigned int* __restrict__ flags,        // NWG monotone flags (zeroed per launch)
    unsigned short* __restrict__ Xnext,      // bf16 (B*T,1024) or nullptr
    float* __restrict__ yout,                // f32 (B*T,1024) (top layer) or nullptr
    float* __restrict__ hT, float* __restrict__ cT) {
  extern __shared__ char dynpad_[];          // sized 57344 at launch -> forces 1 WG/CU
  __shared__ short Wl[16 * 1024];            // 32KB, swizzled
  __shared__ float zs[4][2][64][4];          // 8KB
  __shared__ float biasS[16];
  (void)dynpad_;
  int wg = blockIdx.x, tid = threadIdx.x, lane = tid & 63, wv = tid >> 6;

  // stage Wh^T slice into LDS with XOR swizzle (rows r=g*4+q -> global col g*1024+wg*4+q)
  for (int cch = tid; cch < 2048; cch += 256) {
    int off = cch * 16;
    int r = off >> 11;
    int rowoff = off & 2047;
    int n = (r >> 2) * 1024 + wg * 4 + (r & 3);
    short8 v = *(const short8*)&WhT[(size_t)n * 1024 + (rowoff >> 1)];
    *(short8*)((char*)Wl + (off ^ ((r & 7) << 4))) = v;
  }
  if (tid < 16) biasS[tid] = bias[(tid >> 2) * 1024 + wg * 4 + (tid & 3)];
  __syncthreads();

  int p = tid, bb = p >> 2, q = p & 3;
  float cst = 0.f;
  int l15 = lane & 15, lh = lane >> 4;
  bool act = (p < 128);

  for (int t = 0; t < T_; ++t) {
    // ---- prefetch this step's Zin gate pre-activations (independent of barrier) ----
    unsigned short zv0 = 0, zv1 = 0, zv2 = 0, zv3 = 0;
    if (act) {
      const unsigned short* zrow = Zin + (size_t)(bb * T_ + t) * NG + wg * 4 + q;
      zv0 = zrow[0];
      zv1 = zrow[1024];
      zv2 = zrow[2048];
      zv3 = zrow[3072];
    }
    // ---- barrier wait: all WGs finished step t-1 (relaxed polling, no fences) ----
    if (t > 0) {
      if (wv == 0) {
        const unsigned* fl = flags + lane * 4;
        unsigned tt = (unsigned)t;
        for (;;) {
          unsigned f0 = __hip_atomic_load(fl + 0, __ATOMIC_RELAXED, __HIP_MEMORY_SCOPE_AGENT);
          unsigned f1 = __hip_atomic_load(fl + 1, __ATOMIC_RELAXED, __HIP_MEMORY_SCOPE_AGENT);
          unsigned f2 = __hip_atomic_load(fl + 2, __ATOMIC_RELAXED, __HIP_MEMORY_SCOPE_AGENT);
          unsigned f3 = __hip_atomic_load(fl + 3, __ATOMIC_RELAXED, __HIP_MEMORY_SCOPE_AGENT);
          if (__all(f0 >= tt && f1 >= tt && f2 >= tt && f3 >= tt)) break;
          __builtin_amdgcn_s_sleep(1);
        }
        // amortized cache invalidate: clear lines before rotating slot reuse
        if ((t & (HDEPTH - 1)) == 0)
          __builtin_amdgcn_fence(__ATOMIC_ACQUIRE, "agent");
      }
      __syncthreads();
    }
    // ---- recurrent GEMM: z = h(t-1) @ WhT_slice ----
    f32x4 a0 = {}, a1 = {};
    if (t > 0) {
      const unsigned short* hb = hh + (size_t)((t - 1) & (HDEPTH - 1)) * HSTEP;
      int kbase = wv * 256 + lh * 8;
      int bb4a = l15 * 4, bb4b = (16 + l15) * 4;
      for (int kk = 0; kk < 8; ++kk) {
        int k = kbase + kk * 32;
        int base = (k >> 2) * 128;
        unsigned long long u0 = *(const unsigned long long*)&hb[base + bb4a];
        unsigned long long u1 = *(const unsigned long long*)&hb[base + 128 + bb4a];
        unsigned long long u2 = *(const unsigned long long*)&hb[base + bb4b];
        unsigned long long u3 = *(const unsigned long long*)&hb[base + 128 + bb4b];
        bf16x8 av0, av1;
        ((unsigned long long*)&av0)[0] = u0; ((unsigned long long*)&av0)[1] = u1;
        ((unsigned long long*)&av1)[0] = u2; ((unsigned long long*)&av1)[1] = u3;
        bf16x8 bv = *(const bf16x8*)((const char*)Wl + (((l15 * 1024 + k) * 2) ^ ((l15 & 7) << 4)));
        a0 = __builtin_amdgcn_mfma_f32_16x16x32_bf16(av0, bv, a0, 0, 0, 0);
        a1 = __builtin_amdgcn_mfma_f32_16x16x32_bf16(av1, bv, a1, 0, 0, 0);
      }
    }
    *(f32x4*)&zs[wv][0][lane][0] = a0;
    *(f32x4*)&zs[wv][1][lane][0] = a1;
    __syncthreads();
    if (act) {
      int mi = bb >> 4, lx = ((bb & 15) >> 2) * 16, rg = bb & 3;
      float zg[4];
      unsigned short zvv[4] = {zv0, zv1, zv2, zv3};
      for (int g = 0; g < 4; ++g) {
        int r = g * 4 + q;
        float z = zs[0][mi][lx + r][rg] + zs[1][mi][lx + r][rg] +
                  zs[2][mi][lx + r][rg] + zs[3][mi][lx + r][rg];
        zg[g] = z + bf2f(zvv[g]) + biasS[r];
      }
      float ig = 1.f / (1.f + __expf(-zg[0]));
      float fg = 1.f / (1.f + __expf(-zg[1]));
      float e2 = __expf(-2.f * fabsf(zg[2]));
      float gg = copysignf((1.f - e2) / (1.f + e2), zg[2]);
      float og = 1.f / (1.f + __expf(-zg[3]));
      cst = fg * cst + ig * gg;
      float e2c = __expf(-2.f * fabsf(cst));
      float th = copysignf((1.f - e2c) / (1.f + e2c), cst);
      float hv = og * th;
      unsigned short hw = f2bf(hv);
      int u = wg * 4 + q;
      // h store: write-through to device coherence point (MALL), compact layout
      unsigned short* haddr = hh + (size_t)(t & (HDEPTH - 1)) * HSTEP + wg * 128 + p;
      unsigned hw32 = hw;
      asm volatile("global_store_short %0, %1, off sc0 sc1"
                   :: "v"(haddr), "v"(hw32) : "memory");
      // streaming outputs: nontemporal, keep L2 clean
      size_t xrow = (size_t)(bb * T_ + t) * 1024 + u;
      if (Xnext) __builtin_nontemporal_store(hw, &Xnext[xrow]);
      else __builtin_nontemporal_store(hv, &yout[xrow]);
      if (t == T_ - 1) { hT[bb * 1024 + u] = hv; cT[bb * 1024 + u] = cst; }
    }
    // drain asm h-stores (compiler doesn't track them) before signaling
    asm volatile("s_waitcnt vmcnt(0)" ::: "memory");
    __syncthreads();
    if (t < T_ - 1 && tid == 0) {
      __hip_atomic_store(&flags[wg], (unsigned)(t + 1), __ATOMIC_RELAXED, __HIP_MEMORY_SCOPE_AGENT);
    }
  }
}

extern "C" void kernel_launch(void* const* d_in, const int* in_sizes, int n_in,
                              void* d_out, int out_size, void* d_ws, size_t ws_size,
                              hipStream_t stream) {
  const float* x = (const float*)d_in[0];
  const float* Wi = (const float*)d_in[1];
  const float* Wh = (const float*)d_in[2];
  const float* bias = (const float*)d_in[3];
  float* out = (float*)d_out;
  uint8_t* W = (uint8_t*)d_ws;

  unsigned* flagsBase = (unsigned*)W;                               // 3 x 1KB flag arrays
  unsigned short* hh  = (unsigned short*)(W + 0x100000);            // 4MB rotating h buffers
  unsigned short* Zin = (unsigned short*)(W + 0x500000);            // 128MB bf16 (B*T,4096)
  unsigned short* Xa  = (unsigned short*)(W + 0x8500000);           // 32MB bf16 (B*T,1024)
  unsigned short* Xb  = (unsigned short*)(W + 0xA500000);           // 32MB
  unsigned short* WiT = (unsigned short*)(W + 0xC500000);           // 24MB bf16 (L,4096,1024)
  unsigned short* WhT = (unsigned short*)(W + 0xDD00000);           // 24MB (ends 0xF500000)

  hipMemsetAsync(d_ws, 0, 4096, stream);
  k_conv<<<8192, 256, 0, stream>>>(x, Xa, (B_ * T_ * D_) / 8);
  k_transw<<<dim3(32, 128, 3), 256, 0, stream>>>(Wi, WiT);
  k_transw<<<dim3(32, 128, 3), 256, 0, stream>>>(Wh, WhT);

  float* yout = out;
  float* hT = out + 16777216;
  float* cT = out + 16777216 + 98304;
  unsigned short* Xcur = Xa;
  unsigned short* Xnxt = Xb;
  for (int l = 0; l < L_; ++l) {
    k_gemm_in<<<4096, 256, 0, stream>>>(Xcur, WiT + (size_t)l * NG * 1024, Zin);
    k_rec<<<NWG, 256, 57344, stream>>>(WhT + (size_t)l * NG * 1024, Zin, bias + l * NG,
                                       hh, flagsBase + l * 256,
                                       (l < 2) ? Xnxt : (unsigned short*)nullptr,
                                       (l < 2) ? (float*)nullptr : yout,
                                       hT + l * (B_ * H_), cT + l * (B_ * H_));
    unsigned short* tmp = Xcur; Xcur = Xnxt; Xnxt = tmp;
  }
}

// Round 4
// 4171.882 us; speedup vs baseline: 9.2287x; 1.5010x over previous
//
#include <hip/hip_runtime.h>
#include <hip/hip_bf16.h>
#include <stdint.h>

typedef __bf16 bf16x8 __attribute__((ext_vector_type(8)));
typedef float f32x4 __attribute__((ext_vector_type(4)));
typedef short short8 __attribute__((ext_vector_type(8)));
typedef unsigned long long u64;

#define B_ 32
#define T_ 512
#define D_ 1024
#define NG 4096
#define L_ 3
#define HD 32            // rotating h step-buffer depth
#define HSLOT 32768      // ushorts per slot (32 batches x 1024 units)
#define NWG3 192
#define NSTEP 514

__device__ inline unsigned short f2bf(float f) {
  unsigned u = __float_as_uint(f);
  unsigned r = (u + 0x7fffu + ((u >> 16) & 1u)) >> 16;
  return (unsigned short)r;
}
__device__ inline float bf2f(unsigned short h) {
  return __uint_as_float(((unsigned)h) << 16);
}
__device__ __forceinline__ float sigm(float x) { return 1.f / (1.f + __expf(-x)); }
__device__ __forceinline__ float tanh_(float x) {
  float e2 = __expf(-2.f * fabsf(x));
  return copysignf((1.f - e2) / (1.f + e2), x);
}

// ---------------- f32 -> bf16 convert (vectorized) ----------------
__global__ __launch_bounds__(256) void k_conv(const float* __restrict__ in,
                                              unsigned short* __restrict__ out, int n8) {
  int i = blockIdx.x * 256 + threadIdx.x;
  if (i >= n8) return;
  const float4* p = (const float4*)(in) + (size_t)i * 2;
  float4 a = p[0], b = p[1];
  short8 o;
  o[0] = (short)f2bf(a.x); o[1] = (short)f2bf(a.y); o[2] = (short)f2bf(a.z); o[3] = (short)f2bf(a.w);
  o[4] = (short)f2bf(b.x); o[5] = (short)f2bf(b.y); o[6] = (short)f2bf(b.z); o[7] = (short)f2bf(b.w);
  *((short8*)out + i) = o;
}

// ---------------- transpose+convert weights: (L,K,N) f32 -> (L,N,K) bf16 ----------------
__global__ __launch_bounds__(256) void k_transw(const float* __restrict__ in,
                                                unsigned short* __restrict__ out) {
  __shared__ float Tt[32][33];
  int k0 = blockIdx.x * 32, n0 = blockIdx.y * 32, l = blockIdx.z;
  const float* ip = in + (size_t)l * D_ * NG;
  unsigned short* op = out + (size_t)l * NG * D_;
  int r = threadIdx.x >> 5, c = threadIdx.x & 31;
  for (int rr = r; rr < 32; rr += 8)
    Tt[rr][c] = ip[(size_t)(k0 + rr) * NG + n0 + c];
  __syncthreads();
  for (int rr = r; rr < 32; rr += 8)
    op[(size_t)(n0 + rr) * D_ + k0 + c] = f2bf(Tt[c][rr]);
}

// ---------------- input-path GEMM (layer 0 only): Z = X @ Wi0 ----------------
#define PAD 40
__global__ __launch_bounds__(256) void k_gemm_in(const unsigned short* __restrict__ X,
                                                 const unsigned short* __restrict__ WT,
                                                 unsigned short* __restrict__ Z) {
  __shared__ short Al[128 * PAD];
  __shared__ short Bl[128 * PAD];
  int bx = blockIdx.x;
  int m0 = (bx >> 5) * 128, n0 = (bx & 31) * 128;
  int tid = threadIdx.x, lane = tid & 63, wv = tid >> 6;
  int wm = (wv >> 1) * 64, wn = (wv & 1) * 64;
  int l15 = lane & 15, lh = lane >> 4;
  f32x4 acc[4][4] = {};
  for (int s = 0; s < 32; ++s) {
    int k0 = s * 32;
    __syncthreads();
    for (int rr = 0; rr < 2; ++rr) {
      int ch = rr * 256 + tid;
      int row = ch >> 2, ko = (ch & 3) * 8;
      *(short8*)&Al[row * PAD + ko] = *(const short8*)&X[(size_t)(m0 + row) * 1024 + k0 + ko];
      *(short8*)&Bl[row * PAD + ko] = *(const short8*)&WT[(size_t)(n0 + row) * 1024 + k0 + ko];
    }
    __syncthreads();
    bf16x8 af[4], bfr[4];
    for (int mi = 0; mi < 4; ++mi)
      af[mi] = *(const bf16x8*)&Al[(wm + mi * 16 + l15) * PAD + lh * 8];
    for (int ni = 0; ni < 4; ++ni)
      bfr[ni] = *(const bf16x8*)&Bl[(wn + ni * 16 + l15) * PAD + lh * 8];
    for (int mi = 0; mi < 4; ++mi)
      for (int ni = 0; ni < 4; ++ni)
        acc[mi][ni] = __builtin_amdgcn_mfma_f32_16x16x32_bf16(af[mi], bfr[ni], acc[mi][ni], 0, 0, 0);
  }
  for (int mi = 0; mi < 4; ++mi)
    for (int ni = 0; ni < 4; ++ni)
      for (int r2 = 0; r2 < 4; ++r2) {
        int row = m0 + wm + mi * 16 + (lane >> 4) * 4 + r2;
        int col = n0 + wn + ni * 16 + l15;
        Z[(size_t)row * NG + col] = f2bf(acc[mi][ni][r2]);
      }
}

// ---------------- fused wavefronted 3-layer persistent recurrent kernel ----------------
// 192 WGs x 512 threads. WGs [0,64): layer0, [64,128): layer1, [128,192): layer2.
// Global step s: layer l computes t = s - l. Single flag barrier per step.
// Each WG owns 16 h-units (64 z-cols = 4 gates x 16). 8 waves split fused K.
//   layer0: K=1024 (recurrent Wh0 only; input gates precomputed in Zin0). 128 K/wave.
//   layer1/2: K=2048 ([x=h_{l-1}; h_l] @ [Wi;Wh]). waves 0-3: input, 4-7: recurrent.
// All weight B-fragments live in VGPRs (loaded once). LDS = 64KB split-K reduce buf.
// h exchange: rotating 32-deep slots, write-through sc0/sc1 stores, relaxed flags,
// acquire fence every 32 steps before slot reuse (cross-call safe: fence at s=512
// plus fence-before-first-reuse covers all cached lines).
template<int LAY>
__device__ __forceinline__ void rec_body(
    const unsigned short* __restrict__ WiL, const unsigned short* __restrict__ WhL,
    const unsigned short* __restrict__ Zin0, const float* __restrict__ biasL,
    unsigned short* __restrict__ hh, unsigned int* __restrict__ flags,
    float* __restrict__ yout, float* __restrict__ hT, float* __restrict__ cT,
    int wgl, float* zsb) {
  int tid = threadIdx.x, lane = tid & 63, kw = tid >> 6;
  int l15 = lane & 15, lh = lane >> 4;
  int U = wgl * 16;
  constexpr int NKF = (LAY == 0) ? 4 : 8;   // K-frags per wave (kspan = NKF*32)

  // ---- load this wave's weight B-fragments into VGPRs (once) ----
  bf16x8 bw[4 * NKF];
  {
    const unsigned short* Wsrc;
    int k0;
    if (LAY == 0) { Wsrc = WhL; k0 = kw * 128; }
    else { Wsrc = (kw < 4) ? WiL : WhL; k0 = (kw & 3) * 256; }
#pragma unroll
    for (int nt = 0; nt < 4; ++nt)
#pragma unroll
      for (int kf = 0; kf < NKF; ++kf)
        bw[nt * NKF + kf] =
            *(const bf16x8*)&Wsrc[(size_t)(nt * 1024 + U + l15) * 1024 + k0 + kf * 32 + lh * 8];
  }

  // elementwise cell: thread -> (batch b, unit j)
  int b = tid >> 4, j = tid & 15;
  int u = U + j;
  float bz0 = biasL[u], bz1 = biasL[1024 + u], bz2 = biasL[2048 + u], bz3 = biasL[3072 + u];
  float cst = 0.f;
  unsigned short* hhme = hh + (size_t)LAY * HD * HSLOT;
  const unsigned short* hhin = (LAY == 0) ? hhme : hh + (size_t)(LAY - 1) * HD * HSLOT;

  for (int s = 0; s < NSTEP; ++s) {
    int t = s - LAY;
    bool active = (t >= 0) && (t < T_);
    // ---- Zin prefetch (layer 0 only; independent of barrier) ----
    unsigned short zv0 = 0, zv1 = 0, zv2 = 0, zv3 = 0;
    if (LAY == 0 && active) {
      const unsigned short* zr = Zin0 + (size_t)(b * T_ + t) * NG + u;
      zv0 = zr[0]; zv1 = zr[1024]; zv2 = zr[2048]; zv3 = zr[3072];
    }
    // ---- global barrier: all 192 WGs finished step s-1 ----
    if (s > 0) {
      if (kw == 0) {
        const unsigned* fl = flags + (lane < 48 ? lane : 47) * 4;
        unsigned ss = (unsigned)s;
        for (;;) {
          unsigned f0 = __hip_atomic_load(fl + 0, __ATOMIC_RELAXED, __HIP_MEMORY_SCOPE_AGENT);
          unsigned f1 = __hip_atomic_load(fl + 1, __ATOMIC_RELAXED, __HIP_MEMORY_SCOPE_AGENT);
          unsigned f2 = __hip_atomic_load(fl + 2, __ATOMIC_RELAXED, __HIP_MEMORY_SCOPE_AGENT);
          unsigned f3 = __hip_atomic_load(fl + 3, __ATOMIC_RELAXED, __HIP_MEMORY_SCOPE_AGENT);
          bool ok = (lane >= 48) || ((f0 >= ss) & (f1 >= ss) & (f2 >= ss) & (f3 >= ss));
          if (__all(ok)) break;
          __builtin_amdgcn_s_sleep(1);
        }
        if ((s & (HD - 1)) == 0)
          __builtin_amdgcn_fence(__ATOMIC_ACQUIRE, "agent");  // clear caches before slot reuse
      }
      __syncthreads();
    }
    if (active) {
      // ---- GEMM: this wave's K-slice ----
      const unsigned short* hsrc;
      bool dom;
      if (LAY == 0)      { hsrc = hhme + (size_t)((t - 1) & (HD - 1)) * HSLOT; dom = (t > 0); }
      else if (kw < 4)   { hsrc = hhin + (size_t)(t & (HD - 1)) * HSLOT;       dom = true; }
      else               { hsrc = hhme + (size_t)((t - 1) & (HD - 1)) * HSLOT; dom = (t > 0); }
      f32x4 acc[2][4] = {};
      if (dom) {
#pragma unroll
        for (int kf = 0; kf < NKF; ++kf) {
          int k = (LAY == 0 ? kw * 128 : (kw & 3) * 256) + kf * 32 + lh * 8;
          const unsigned short* pa = hsrc + (k >> 2) * 128;
          u64 x0 = *(const u64*)(pa + l15 * 4);
          u64 x1 = *(const u64*)(pa + 128 + l15 * 4);
          u64 x2 = *(const u64*)(pa + 64 + l15 * 4);
          u64 x3 = *(const u64*)(pa + 192 + l15 * 4);
          bf16x8 a0, a1;
          ((u64*)&a0)[0] = x0; ((u64*)&a0)[1] = x1;
          ((u64*)&a1)[0] = x2; ((u64*)&a1)[1] = x3;
#pragma unroll
          for (int nt = 0; nt < 4; ++nt) {
            acc[0][nt] = __builtin_amdgcn_mfma_f32_16x16x32_bf16(a0, bw[nt * NKF + kf], acc[0][nt], 0, 0, 0);
            acc[1][nt] = __builtin_amdgcn_mfma_f32_16x16x32_bf16(a1, bw[nt * NKF + kf], acc[1][nt], 0, 0, 0);
          }
        }
      }
      // ---- write split-K partials: zs[kw][mt*4+nt][lane][4] (bank-conflict-free) ----
#pragma unroll
      for (int mt = 0; mt < 2; ++mt)
#pragma unroll
        for (int nt = 0; nt < 4; ++nt)
          *(f32x4*)&zsb[(((kw * 8) + mt * 4 + nt) * 64 + lane) * 4] = acc[mt][nt];
    }
    __syncthreads();
    if (active) {
      // ---- reduce 8 partials + gates + state update ----
      int mt = b >> 4, lzs = ((b & 15) >> 2) * 16 + j, r = b & 3;
      float z0 = bz0, z1 = bz1, z2 = bz2, z3 = bz3;
#pragma unroll
      for (int k2 = 0; k2 < 8; ++k2) {
        int base = ((k2 * 8 + mt * 4) * 64 + lzs) * 4 + r;
        z0 += zsb[base];
        z1 += zsb[base + 256];
        z2 += zsb[base + 512];
        z3 += zsb[base + 768];
      }
      if (LAY == 0) { z0 += bf2f(zv0); z1 += bf2f(zv1); z2 += bf2f(zv2); z3 += bf2f(zv3); }
      float ig = sigm(z0), fg = sigm(z1), gg = tanh_(z2), og = sigm(z3);
      cst = fg * cst + ig * gg;
      float hv = og * tanh_(cst);
      unsigned short hw = f2bf(hv);
      unsigned short* ha = hhme + (size_t)(t & (HD - 1)) * HSLOT + (u >> 2) * 128 + b * 4 + (u & 3);
      unsigned hw32 = hw;
      asm volatile("global_store_short %0, %1, off sc0 sc1" :: "v"(ha), "v"(hw32) : "memory");
      if (LAY == 2) __builtin_nontemporal_store(hv, &yout[(size_t)(b * T_ + t) * 1024 + u]);
      if (t == T_ - 1) {
        hT[LAY * (B_ * 1024) + b * 1024 + u] = hv;
        cT[LAY * (B_ * 1024) + b * 1024 + u] = cst;
      }
    }
    // drain asm h-stores before signaling (per-wave), then WG-join, then flag
    asm volatile("s_waitcnt vmcnt(0)" ::: "memory");
    __syncthreads();
    if (tid == 0 && s < NSTEP - 1)
      __hip_atomic_store(&flags[blockIdx.x], (unsigned)(s + 1), __ATOMIC_RELAXED, __HIP_MEMORY_SCOPE_AGENT);
  }
}

__global__ __launch_bounds__(512, 2) void k_rec3(
    const unsigned short* __restrict__ WiT, const unsigned short* __restrict__ WhT,
    const unsigned short* __restrict__ Zin0, const float* __restrict__ bias,
    unsigned short* __restrict__ hh, unsigned int* __restrict__ flags,
    float* __restrict__ yout, float* __restrict__ hT, float* __restrict__ cT) {
  extern __shared__ float zsb[];   // 64KB: [kw][8][64][4] f32
  int wg = blockIdx.x;
  int lay = (wg >= 64) + (wg >= 128);
  int wgl = wg & 63;
  const unsigned short* WiL = WiT + (size_t)lay * NG * 1024;
  const unsigned short* WhL = WhT + (size_t)lay * NG * 1024;
  const float* biasL = bias + lay * NG;
  if (lay == 0)      rec_body<0>(WiL, WhL, Zin0, biasL, hh, flags, yout, hT, cT, wgl, zsb);
  else if (lay == 1) rec_body<1>(WiL, WhL, Zin0, biasL, hh, flags, yout, hT, cT, wgl, zsb);
  else               rec_body<2>(WiL, WhL, Zin0, biasL, hh, flags, yout, hT, cT, wgl, zsb);
}

extern "C" void kernel_launch(void* const* d_in, const int* in_sizes, int n_in,
                              void* d_out, int out_size, void* d_ws, size_t ws_size,
                              hipStream_t stream) {
  const float* x = (const float*)d_in[0];
  const float* Wi = (const float*)d_in[1];
  const float* Wh = (const float*)d_in[2];
  const float* bias = (const float*)d_in[3];
  float* out = (float*)d_out;
  uint8_t* W = (uint8_t*)d_ws;

  unsigned* flags = (unsigned*)W;                                   // 192 flags
  unsigned short* hh  = (unsigned short*)(W + 0x10000);             // 3 x 32 x 64KB = 6MB
  unsigned short* Zin0 = (unsigned short*)(W + 0x800000);           // 128MB bf16 (B*T,4096)
  unsigned short* Xa  = (unsigned short*)(W + 0x8800000);           // 32MB bf16 (B*T,1024)
  unsigned short* WiT = (unsigned short*)(W + 0xA800000);           // 24MB bf16 (L,4096,1024)
  unsigned short* WhT = (unsigned short*)(W + 0xC000000);           // 24MB (ends 0xD800000)

  hipMemsetAsync(d_ws, 0, 4096, stream);
  k_conv<<<8192, 256, 0, stream>>>(x, Xa, (B_ * T_ * D_) / 8);
  k_transw<<<dim3(32, 128, 3), 256, 0, stream>>>(Wi, WiT);
  k_transw<<<dim3(32, 128, 3), 256, 0, stream>>>(Wh, WhT);
  k_gemm_in<<<4096, 256, 0, stream>>>(Xa, WiT, Zin0);   // layer 0 input gates

  float* yout = out;
  float* hT = out + 16777216;
  float* cT = out + 16777216 + 98304;
  k_rec3<<<NWG3, 512, 65536, stream>>>(WiT, WhT, Zin0, bias, hh, flags, yout, hT, cT);
}